// Round 17
// baseline (527.784 us; speedup 1.0000x reference)
//
#include <hip/hip_runtime.h>
#include <hip/hip_bf16.h>

#define N_A 100000
#define N_G 25000
#define DD 128
#define E_B 400000
#define E_O 100000
#define E_R 200000
#define E_P 200000
#define EALL 900000
#define NSLOT 250000
#define STRIDE 64
#define NALL 125000
#define GBN 7813   // ceil(125000/16) node-batch blocks

static constexpr float BN_INV_C = 0.99999500003749969f; // 1/sqrt(1+1e-5)

typedef __attribute__((ext_vector_type(8))) short bf16x8;
typedef __attribute__((ext_vector_type(4))) float f32x4;

__device__ __forceinline__ unsigned short f2bf(float f) {
    unsigned u = __float_as_uint(f);
    unsigned r = (u + 0x7FFFu + ((u >> 16) & 1u)) >> 16;
    return (unsigned short)r;
}
__device__ __forceinline__ float bf2f(unsigned short s) {
    return __uint_as_float(((unsigned)s) << 16);
}
__device__ __forceinline__ float lrelu(float v) { return v > 0.f ? v : 0.2f * v; }

// async global->LDS 16B: LDS dest = (wave-uniform base) + lane*16
__device__ __forceinline__ void gload16(const unsigned short* g, unsigned short* l) {
    __builtin_amdgcn_global_load_lds(
        (const __attribute__((address_space(1))) void*)g,
        (__attribute__((address_space(3))) void*)l, 16, 0, 0);
}

// ---------------- prep: xcast + wcast + war + adj_fill in one launch ----------------
struct WcSeg { const float* src; unsigned short* dst; int K; int N; int ldk; int off; };
struct PrepArgs {
    const float* xa; const float* xg;
    unsigned short* xab; unsigned short* xgb;
    WcSeg wc[10];
    const float* rWfc; const float* ral; const float* rar;
    const float* pWfc; const float* pal; const float* par;
    float* wv;
    const int* bs; const int* bd; const int* os; const int* od;
    const int* rs; const int* rd; const int* ps; const int* pd;
    int* deg; uint2* adj; int* heads; int* nxt;
};

#define PB_XC 15625
#define PB_WC 2560
#define PB_WAR 8

__global__ __launch_bounds__(256) void k_prep(PrepArgs p) {
    int bx = blockIdx.x, tid = threadIdx.x;
    if (bx < PB_XC) {
        int t = bx * 256 + tid;
        if (t < N_A * 32) {
            float4 v = *(const float4*)(p.xa + (size_t)t * 4);
            ushort4 o; o.x = f2bf(v.x); o.y = f2bf(v.y); o.z = f2bf(v.z); o.w = f2bf(v.w);
            *(ushort4*)(p.xab + (size_t)t * 4) = o;
        } else {
            int t2 = t - N_A * 32;
            if (t2 < N_G * 32) {
                float4 v = *(const float4*)(p.xg + (size_t)t2 * 4);
                ushort4 o; o.x = f2bf(v.x); o.y = f2bf(v.y); o.z = f2bf(v.z); o.w = f2bf(v.w);
                *(ushort4*)(p.xgb + (size_t)t2 * 4) = o;
            }
        }
    } else if (bx < PB_XC + PB_WC) {
        int b2 = bx - PB_XC;
        WcSeg sg = p.wc[b2 >> 8];
        int t = ((b2 & 255) << 8) + tid;
        if (t < sg.K * sg.N) {
            int n = t % sg.N, k = t / sg.N;
            sg.dst[(size_t)n * sg.ldk + sg.off + k] = f2bf(sg.src[t]);
        }
    } else if (bx < PB_XC + PB_WC + PB_WAR) {
        int b3 = bx - (PB_XC + PB_WC);
        int bsel = b3 >> 1;
        int t = ((b3 & 1) << 8) + tid;   // 512 threads per bsel
        const float* W = bsel < 2 ? p.rWfc : p.pWfc;
        const float* vec = bsel == 0 ? p.ral : bsel == 1 ? p.rar : bsel == 2 ? p.pal : p.par;
        int k = t >> 2, h = t & 3;
        const float* wr = W + (size_t)k * 512 + h * 128;
        const float* av = vec + h * 128;
        float s = 0.f;
        for (int d = 0; d < 128; ++d) s += wr[d] * av[d];
        p.wv[bsel * 512 + t] = s;
    } else {
        int t = (bx - (PB_XC + PB_WC + PB_WAR)) * 256 + tid;
        int e, base, go; const int* S; const int* D;
        if (t < E_B) { e = t; S = p.bs; D = p.bd; base = 0; go = 0; }
        else if (t < E_B + E_O) { e = t - E_B; S = p.os; D = p.od; base = 100000; go = E_B; }
        else if (t < E_B + E_O + E_R) { e = t - (E_B + E_O); S = p.rs; D = p.rd; base = 125000; go = E_B + E_O; }
        else if (t < EALL) { e = t - (E_B + E_O + E_R); S = p.ps; D = p.pd; base = 225000; go = E_B + E_O + E_R; }
        else return;
        int d = D[e], s = S[e];
        int ns = base + d;
        int pos = atomicAdd(&p.deg[ns], 1);
        if (pos < STRIDE) p.adj[(size_t)ns * STRIDE + pos] = make_uint2((unsigned)e, (unsigned)s);
        else p.nxt[go + e] = atomicExch(&p.heads[ns], e);
    }
}

// per-edge GINE accumulate: lane owns 8 dims at l16*8
__device__ __forceinline__ void gine_acc(const unsigned short* __restrict__ xs,
                                         const float* __restrict__ ef,
                                         uint2 es, int l16, float* acc) {
    uint4 xw = *(const uint4*)(xs + (size_t)es.y * DD + l16 * 8);
    float4 e0 = *(const float4*)(ef + (size_t)es.x * DD + l16 * 8);
    float4 e1 = *(const float4*)(ef + (size_t)es.x * DD + l16 * 8 + 4);
    unsigned w[4] = {xw.x, xw.y, xw.z, xw.w};
    float ev[8] = {e0.x, e0.y, e0.z, e0.w, e1.x, e1.y, e1.z, e1.w};
#pragma unroll
    for (int q = 0; q < 4; ++q) {
        acc[q * 2]     += fmaxf(bf2f((unsigned short)(w[q] & 0xffff)) + ev[q * 2], 0.f);
        acc[q * 2 + 1] += fmaxf(bf2f((unsigned short)(w[q] >> 16)) + ev[q * 2 + 1], 0.f);
    }
}

// ---------------- GINE gather: 16 lanes per node, 4 concurrent nodes per wave ----------------
__device__ __forceinline__ void gine16_body(
    int bx, int tid,
    const unsigned short* __restrict__ xAb, const unsigned short* __restrict__ xGb,
    const float* __restrict__ efB, const float* __restrict__ efO,
    const int* __restrict__ bsrc, const int* __restrict__ osrc,
    const int* __restrict__ deg, const uint2* __restrict__ adj,
    const int* __restrict__ heads, const int* __restrict__ nxt,
    const float* __restrict__ beps, const float* __restrict__ oeps,
    unsigned short* __restrict__ h0A, unsigned short* __restrict__ h0G,
    uint2* glbuf, int* degb) {
    int wid = tid >> 6, lane = tid & 63;
    int grp = lane >> 4, l16 = lane & 15;
    int nbase = bx * 16 + wid * 4;
    bool atomside = nbase < N_A;   // 100000 is 16-aligned -> wave-uniform
    const unsigned short* xs = atomside ? xAb : xGb;
    const float* ef = atomside ? efB : efO;
    const int* esrc = atomside ? bsrc : osrc;
    const int* nx = atomside ? nxt : nxt + E_B;
    float ep = 1.0f + (atomside ? beps[0] : oeps[0]);
    unsigned short* h0 = atomside ? h0A : h0G;
    uint2* glw = glbuf + wid * 4 * STRIDE;
#pragma unroll
    for (int j = 0; j < 4; ++j) {
        int nj = nbase + j;
        if (nj < NALL) glw[j * STRIDE + lane] = adj[(size_t)nj * STRIDE + lane];
    }
    if (lane < 4) {
        int nj = nbase + lane;
        degb[wid * 4 + lane] = (nj < NALL) ? deg[nj] : 0;
    }
    __syncthreads();
    int nj = nbase + grp;
    if (nj >= NALL) return;
    int dd = degb[wid * 4 + grp];
    int cb = min(dd, STRIDE);
    int nn = atomside ? nj : nj - N_A;
    const uint2* gl = glw + grp * STRIDE;
    float acc[8] = {0.f, 0.f, 0.f, 0.f, 0.f, 0.f, 0.f, 0.f};
    int i = 0;
    for (; i + 2 <= cb; i += 2) {
        gine_acc(xs, ef, gl[i], l16, acc);
        gine_acc(xs, ef, gl[i + 1], l16, acc);
    }
    if (i < cb) gine_acc(xs, ef, gl[i], l16, acc);
    if (dd > STRIDE) {
        for (int e = heads[nj]; e >= 0; e = nx[e])
            gine_acc(xs, ef, make_uint2((unsigned)e, (unsigned)esrc[e]), l16, acc);
    }
    uint4 xd = *(const uint4*)(xs + (size_t)nn * DD + l16 * 8);
    unsigned w[4] = {xd.x, xd.y, xd.z, xd.w};
    uint4 o;
    unsigned ow[4];
#pragma unroll
    for (int q = 0; q < 4; ++q) {
        float v0 = ep * bf2f((unsigned short)(w[q] & 0xffff)) + acc[q * 2];
        float v1 = ep * bf2f((unsigned short)(w[q] >> 16)) + acc[q * 2 + 1];
        ow[q] = (unsigned)f2bf(v0) | ((unsigned)f2bf(v1) << 16);
    }
    o.x = ow[0]; o.y = ow[1]; o.z = ow[2]; o.w = ow[3];
    *(uint4*)(h0 + (size_t)nn * DD + l16 * 8) = o;
}

// ---------------- node logits body ----------------
__device__ __forceinline__ void logit_body(
    int t,
    const unsigned short* __restrict__ xAb, const unsigned short* __restrict__ xGb,
    const float* __restrict__ wv,
    float* __restrict__ elR, float* __restrict__ elP,
    float* __restrict__ erR, float* __restrict__ erP) {
    const unsigned short* xr; const float* wl; const float* wr_; float* ol; float* orr; int idx;
    if (t < N_A * 4) {
        idx = t; xr = xAb + (size_t)(t >> 2) * DD; wl = wv + 1024; wr_ = wv + 512;
        ol = elP; orr = erR;
    } else {
        int t2 = t - N_A * 4;
        if (t2 >= N_G * 4) return;
        idx = t2; xr = xGb + (size_t)(t2 >> 2) * DD; wl = wv; wr_ = wv + 1536;
        ol = elR; orr = erP;
    }
    int h = idx & 3;
    float sl = 0.f, sr = 0.f;
#pragma unroll
    for (int k = 0; k < DD; k += 8) {
        uint4 w = *(const uint4*)(xr + k);
        unsigned wa[4] = {w.x, w.y, w.z, w.w};
#pragma unroll
        for (int q = 0; q < 4; ++q) {
            float x0 = bf2f((unsigned short)(wa[q] & 0xffff));
            float x1 = bf2f((unsigned short)(wa[q] >> 16));
            int k0 = (k + q * 2) * 4 + h, k1 = (k + q * 2 + 1) * 4 + h;
            sl += x0 * wl[k0] + x1 * wl[k1];
            sr += x0 * wr_[k0] + x1 * wr_[k1];
        }
    }
    ol[idx] = sl;
    orr[idx] = sr;
}

__global__ __launch_bounds__(256) void k_gather_logit(
    const unsigned short* __restrict__ xAb, const unsigned short* __restrict__ xGb,
    const float* __restrict__ efB, const float* __restrict__ efO,
    const int* __restrict__ bsrc, const int* __restrict__ osrc,
    const int* __restrict__ deg, const uint2* __restrict__ adj,
    const int* __restrict__ heads, const int* __restrict__ nxt,
    const float* __restrict__ beps, const float* __restrict__ oeps,
    unsigned short* __restrict__ h0A, unsigned short* __restrict__ h0G,
    const float* __restrict__ wv,
    float* __restrict__ elR, float* __restrict__ elP,
    float* __restrict__ erR, float* __restrict__ erP) {
    __shared__ uint2 gl[16 * STRIDE];
    __shared__ int degb[16];
    int bx = blockIdx.x;
    if (bx < GBN)
        gine16_body(bx, threadIdx.x, xAb, xGb, efB, efO, bsrc, osrc, deg, adj, heads, nxt,
                    beps, oeps, h0A, h0G, gl, degb);
    else
        logit_body((bx - GBN) * 256 + threadIdx.x, xAb, xGb, wv, elR, elP, erR, erP);
}

// ---------------- edge-parallel exp + denominator body ----------------
__device__ __forceinline__ void exp_body(
    int t,
    const float* __restrict__ elR, const float* __restrict__ erR,
    const float* __restrict__ elP, const float* __restrict__ erP,
    const int* __restrict__ rs, const int* __restrict__ rd,
    const int* __restrict__ ps, const int* __restrict__ pd,
    float* __restrict__ exR, float* __restrict__ exP,
    float* __restrict__ denR, float* __restrict__ denP) {
    if (t < E_R * 4) {
        int e = t >> 2, h = t & 3;
        float v = lrelu(elR[rs[e] * 4 + h] + erR[rd[e] * 4 + h]);
        float x = __expf(v);
        exR[t] = x;
        atomicAdd(&denR[rd[e] * 4 + h], x);
    } else {
        int t2 = t - E_R * 4;
        if (t2 >= E_P * 4) return;
        int e = t2 >> 2, h = t2 & 3;
        float v = lrelu(elP[ps[e] * 4 + h] + erP[pd[e] * 4 + h]);
        float x = __expf(v);
        exP[t2] = x;
        atomicAdd(&denP[pd[e] * 4 + h], x);
    }
}

// per-edge GAT accumulate: lane owns 8 dims
__device__ __forceinline__ void att_acc(const unsigned short* __restrict__ xs,
                                        const float* __restrict__ ex,
                                        uint2 es, int l16, const float* inv,
                                        float acc[4][8]) {
    float4 e4 = *(const float4*)(ex + (size_t)es.x * 4);
    uint4 xw = *(const uint4*)(xs + (size_t)es.y * DD + l16 * 8);
    unsigned w[4] = {xw.x, xw.y, xw.z, xw.w};
    float xv[8];
#pragma unroll
    for (int q = 0; q < 4; ++q) {
        xv[q * 2] = bf2f((unsigned short)(w[q] & 0xffff));
        xv[q * 2 + 1] = bf2f((unsigned short)(w[q] >> 16));
    }
    float a[4] = {e4.x * inv[0], e4.y * inv[1], e4.z * inv[2], e4.w * inv[3]};
#pragma unroll
    for (int h = 0; h < 4; ++h)
#pragma unroll
        for (int q = 0; q < 8; ++q) acc[h][q] += a[h] * xv[q];
}

// ---------------- GAT gather: 16 lanes per node, 4 concurrent nodes per wave ----------------
__global__ __launch_bounds__(256) void k_att_gather_all(
    const unsigned short* __restrict__ xAb, const unsigned short* __restrict__ xGb,
    const float* __restrict__ exR, const float* __restrict__ exP,
    const float* __restrict__ denR, const float* __restrict__ denP,
    const int* __restrict__ rsrc, const int* __restrict__ psrc,
    const int* __restrict__ deg, const uint2* __restrict__ adj,
    const int* __restrict__ heads, const int* __restrict__ nxt,
    unsigned short* __restrict__ A2r, unsigned short* __restrict__ A2p) {
    __shared__ uint2 glbuf[16 * STRIDE];
    __shared__ int degb[16];
    int tid = threadIdx.x;
    int wid = tid >> 6, lane = tid & 63;
    int grp = lane >> 4, l16 = lane & 15;
    int nbase = blockIdx.x * 16 + wid * 4;
    bool atomside = nbase < N_A;
    const unsigned short* xs = atomside ? xGb : xAb;
    const float* ex = atomside ? exR : exP;
    const float* den = atomside ? denR : denP;
    const int* esrc = atomside ? rsrc : psrc;
    const int* nx = atomside ? nxt + (E_B + E_O) : nxt + (E_B + E_O + E_R);
    unsigned short* A2b = atomside ? A2r : A2p;
    uint2* glw = glbuf + wid * 4 * STRIDE;
#pragma unroll
    for (int j = 0; j < 4; ++j) {
        int nj = nbase + j;
        if (nj < NALL) glw[j * STRIDE + lane] = adj[(size_t)(125000 + nj) * STRIDE + lane];
    }
    if (lane < 4) {
        int nj = nbase + lane;
        degb[wid * 4 + lane] = (nj < NALL) ? deg[125000 + nj] : 0;
    }
    __syncthreads();
    int nj = nbase + grp;
    if (nj >= NALL) return;
    int dd = degb[wid * 4 + grp];
    int cb = min(dd, STRIDE);
    int nn = atomside ? nj : nj - N_A;
    const uint2* gl = glw + grp * STRIDE;
    unsigned short* A2 = A2b + (size_t)nn * 512;
    float4 dv = *(const float4*)(den + (size_t)nn * 4);
    float inv[4];
    inv[0] = 1.f / fmaxf(dv.x, 1e-9f);
    inv[1] = 1.f / fmaxf(dv.y, 1e-9f);
    inv[2] = 1.f / fmaxf(dv.z, 1e-9f);
    inv[3] = 1.f / fmaxf(dv.w, 1e-9f);
    float acc[4][8] = {};
    int i = 0;
    for (; i + 2 <= cb; i += 2) {
        att_acc(xs, ex, gl[i], l16, inv, acc);
        att_acc(xs, ex, gl[i + 1], l16, inv, acc);
    }
    if (i < cb) att_acc(xs, ex, gl[i], l16, inv, acc);
    if (dd > STRIDE) {
        for (int e = heads[125000 + nj]; e >= 0; e = nx[e])
            att_acc(xs, ex, make_uint2((unsigned)e, (unsigned)esrc[e]), l16, inv, acc);
    }
#pragma unroll
    for (int h = 0; h < 4; ++h) {
        unsigned ow[4];
#pragma unroll
        for (int q = 0; q < 4; ++q)
            ow[q] = (unsigned)f2bf(acc[h][q * 2]) | ((unsigned)f2bf(acc[h][q * 2 + 1]) << 16);
        uint4 o; o.x = ow[0]; o.y = ow[1]; o.z = ow[2]; o.w = ow[3];
        *(uint4*)(A2 + h * 128 + l16 * 8) = o;
    }
}

// ---------------- bf16 MFMA GEMM body: 4 waves, 128x128 tile, DOUBLE-BUFFERED 2-phase ----------------
// Per K-step: issue next tile's global_load_lds into buf^1 BEFORE computing current buf,
// so the barrier's vmcnt drain overlaps with ds_read+MFMA (T3 minimum-2-phase recipe).
#define STAGE_T(buf, k0s) { \
    int kk = (k0s) + swl * 8; \
    int ra0 = min(row0 + r0s, M - 1); \
    int ra1 = min(row0 + r1s, M - 1); \
    const unsigned short *pa0, *pa1; \
    if (GATK) { \
        if ((k0s) < 128) { pa0 = A + (size_t)ra0 * 512 + col0 + kk; pa1 = A + (size_t)ra1 * 512 + col0 + kk; } \
        else { pa0 = Axd + (size_t)ra0 * 128 + (kk - 128); pa1 = Axd + (size_t)ra1 * 128 + (kk - 128); } \
    } else { pa0 = A + (size_t)ra0 * K + kk; pa1 = A + (size_t)ra1 * K + kk; } \
    unsigned short* dA = As + (buf) * 4096 + wave * 512; \
    unsigned short* dB = Bs + (buf) * 4096 + wave * 512; \
    gload16(pa0, dA); \
    gload16(pa1, dA + 2048); \
    gload16(Bt + (size_t)(col0 + r0s) * K + kk, dB); \
    gload16(Bt + (size_t)(col0 + r1s) * K + kk, dB + 2048); \
}

template <int EPI, int OUTBF, int GATK>
__device__ __forceinline__ void gemm_body(
    const unsigned short* __restrict__ A, const unsigned short* __restrict__ Bt,
    void* __restrict__ C, int M, int N, int K,
    const float* __restrict__ bias, const float* __restrict__ g,
    const float* __restrict__ be, const unsigned short* __restrict__ addbf,
    const unsigned short* __restrict__ Axd, int bxx, int byy,
    unsigned short* As, unsigned short* Bs) {
    int tid = threadIdx.x;
    int wave = tid >> 6, lane = tid & 63;
    int wr = wave >> 1, wc = wave & 1;
    int row0 = byy * 128, col0 = bxx * 128;
    int l16 = lane & 15, q = lane >> 4;
    int r0s = wave * 16 + (lane >> 2);
    int r1s = r0s + 64;
    int swl = (lane ^ (lane >> 2) ^ (lane >> 4)) & 3;
    int swr = (l16 ^ (l16 >> 2)) & 3;
    f32x4 acc[4][4] = {};
    STAGE_T(0, 0);
    __syncthreads();
    int cur = 0;
    for (int k0 = 0; k0 < K; k0 += 32) {
        if (k0 + 32 < K) STAGE_T(cur ^ 1, k0 + 32);   // prefetch next tile (in flight across compute)
        const unsigned short* Ab = As + cur * 4096;
        const unsigned short* Bb = Bs + cur * 4096;
        bf16x8 af[4], bfr[4];
#pragma unroll
        for (int i = 0; i < 4; ++i) {
            int row = wr * 64 + i * 16 + l16;
            af[i] = *(const bf16x8*)(&Ab[row * 32 + ((q ^ swr) * 8)]);
        }
#pragma unroll
        for (int j = 0; j < 4; ++j) {
            int row = wc * 64 + j * 16 + l16;
            bfr[j] = *(const bf16x8*)(&Bb[row * 32 + ((q ^ swr) * 8)]);
        }
#pragma unroll
        for (int i = 0; i < 4; ++i)
#pragma unroll
            for (int j = 0; j < 4; ++j)
                acc[i][j] = __builtin_amdgcn_mfma_f32_16x16x32_bf16(af[i], bfr[j], acc[i][j], 0, 0, 0);
        __syncthreads();   // drains this step's prefetch (issued before compute) + readers of cur
        cur ^= 1;
    }
    int rq = (lane >> 4) * 4;
#pragma unroll
    for (int i = 0; i < 4; ++i) {
#pragma unroll
        for (int reg = 0; reg < 4; ++reg) {
            int r = row0 + wr * 64 + i * 16 + rq + reg;
            if (r >= M) continue;
#pragma unroll
            for (int j = 0; j < 4; ++j) {
                int c = col0 + wc * 64 + j * 16 + l16;
                float v = acc[i][j][reg];
                size_t idx = (size_t)r * N + c;
                v += bias[c];
                if (EPI == 2) {
                    v = g[c] * (v * BN_INV_C) + be[c];
                    v = fmaxf(v, 0.f);
                }
                if (EPI == 3) {
                    ((float*)C)[idx] = v + bf2f(addbf[idx]);
                } else if (OUTBF) {
                    ((unsigned short*)C)[idx] = f2bf(v);
                } else {
                    ((float*)C)[idx] = v;
                }
            }
        }
    }
}

#define NBA 782
#define NBG 196

// GINE GEMM1 (both relations) + edge exp: 1956 + 6250 blocks
__global__ __launch_bounds__(256) void k_gemm1_exp(
    const unsigned short* h0A, const unsigned short* h0G,
    const unsigned short* WtB1, const unsigned short* WtO1,
    const float* bb1, const float* bg1, const float* bbe1,
    const float* ob1, const float* og1, const float* obe1,
    unsigned short* R4a, unsigned short* R4g,
    const float* elR, const float* erR, const float* elP, const float* erP,
    const int* rs, const int* rd, const int* ps, const int* pd,
    float* exR, float* exP, float* denR, float* denP) {
    __shared__ unsigned short As[8192];
    __shared__ unsigned short Bs[8192];
    int b = blockIdx.x;
    if (b < 2 * NBA)
        gemm_body<2, 1, 0>(h0A, WtB1, R4a, N_A, 256, 128, bb1, bg1, bbe1, nullptr, nullptr,
                           b & 1, b >> 1, As, Bs);
    else if (b < 2 * NBA + 2 * NBG) {
        int b2 = b - 2 * NBA;
        gemm_body<2, 1, 0>(h0G, WtO1, R4g, N_G, 256, 128, ob1, og1, obe1, nullptr, nullptr,
                           b2 & 1, b2 >> 1, As, Bs);
    } else {
        int t = (b - (2 * NBA + 2 * NBG)) * 256 + threadIdx.x;
        exp_body(t, elR, erR, elP, erP, rs, rd, ps, pd, exR, exP, denR, denP);
    }
}

// GINE GEMM2 (978) + GATK GEMMs (3912): homogeneous gemm blocks
__global__ __launch_bounds__(256) void k_gatk_mid(
    const unsigned short* R4a, const unsigned short* R4g,
    const unsigned short* WtB2, const unsigned short* WtO2,
    const float* bb2, const float* ob2,
    unsigned short* G1a, unsigned short* G1g,
    const unsigned short* A2r, const unsigned short* A2p,
    const unsigned short* xAb, const unsigned short* xGb,
    const unsigned short* WtR, const unsigned short* WtP,
    const float* rbias, const float* rg, const float* rb,
    const float* pbias, const float* pg, const float* pb,
    unsigned short* R3r, unsigned short* R3p) {
    __shared__ unsigned short As[8192];
    __shared__ unsigned short Bs[8192];
    int b = blockIdx.x;
    if (b < NBA)
        gemm_body<1, 1, 0>(R4a, WtB2, G1a, N_A, 128, 256, bb2, nullptr, nullptr, nullptr, nullptr,
                           0, b, As, Bs);
    else if (b < NBA + NBG)
        gemm_body<1, 1, 0>(R4g, WtO2, G1g, N_G, 128, 256, ob2, nullptr, nullptr, nullptr, nullptr,
                           0, b - NBA, As, Bs);
    else if (b < NBA + NBG + 4 * NBA) {
        int b3 = b - (NBA + NBG);
        gemm_body<2, 1, 1>(A2r, WtR, R3r, N_A, 512, 256, rbias, rg, rb, nullptr, xAb,
                           b3 & 3, b3 >> 2, As, Bs);
    } else {
        int b4 = b - (NBA + NBG + 4 * NBA);
        gemm_body<2, 1, 1>(A2p, WtP, R3p, N_G, 512, 256, pbias, pg, pb, nullptr, xGb,
                           b4 & 3, b4 >> 2, As, Bs);
    }
}

// Wout GEMMs (both): 978 blocks, single f32 write of d_out
__global__ __launch_bounds__(256) void k_gemm_out(
    const unsigned short* R3r, const unsigned short* R3p,
    const unsigned short* WtRo, const unsigned short* WtPo,
    const float* rbout, const float* pbout,
    const unsigned short* G1a, const unsigned short* G1g,
    float* out) {
    __shared__ unsigned short As[8192];
    __shared__ unsigned short Bs[8192];
    int b = blockIdx.x;
    if (b < NBA)
        gemm_body<3, 0, 0>(R3r, WtRo, out, N_A, 128, 512, rbout, nullptr, nullptr, G1a, nullptr,
                           0, b, As, Bs);
    else
        gemm_body<3, 0, 0>(R3p, WtPo, out + (size_t)N_A * DD, N_G, 128, 512, pbout, nullptr, nullptr,
                           G1g, nullptr, 0, b - NBA, As, Bs);
}

extern "C" void kernel_launch(void* const* d_in, const int* in_sizes, int n_in,
                              void* d_out, int out_size, void* d_ws, size_t ws_size,
                              hipStream_t stream) {
    const float* x_atom = (const float*)d_in[0];
    const float* x_group = (const float*)d_in[1];
    const float* ef_bond = (const float*)d_in[2];
    const float* ef_ov = (const float*)d_in[3];
    const int* bond_src = (const int*)d_in[4];
    const int* bond_dst = (const int*)d_in[5];
    const int* ov_src = (const int*)d_in[6];
    const int* ov_dst = (const int*)d_in[7];
    const int* ref_src = (const int*)d_in[8];
    const int* ref_dst = (const int*)d_in[9];
    const int* pool_src = (const int*)d_in[10];
    const int* pool_dst = (const int*)d_in[11];
    const float* b_eps = (const float*)d_in[12];
    const float* b_W1 = (const float*)d_in[13];
    const float* b_b1 = (const float*)d_in[14];
    const float* b_g1 = (const float*)d_in[15];
    const float* b_be1 = (const float*)d_in[16];
    const float* b_W2 = (const float*)d_in[17];
    const float* b_b2 = (const float*)d_in[18];
    const float* o_eps = (const float*)d_in[19];
    const float* o_W1 = (const float*)d_in[20];
    const float* o_b1 = (const float*)d_in[21];
    const float* o_g1 = (const float*)d_in[22];
    const float* o_be1 = (const float*)d_in[23];
    const float* o_W2 = (const float*)d_in[24];
    const float* o_b2 = (const float*)d_in[25];
    const float* r_Wfc = (const float*)d_in[26];
    const float* r_al = (const float*)d_in[27];
    const float* r_ar = (const float*)d_in[28];
    const float* r_Wres = (const float*)d_in[29];
    const float* r_bias = (const float*)d_in[30];
    const float* r_g = (const float*)d_in[31];
    const float* r_b = (const float*)d_in[32];
    const float* r_Wout = (const float*)d_in[33];
    const float* r_bout = (const float*)d_in[34];
    const float* p_Wfc = (const float*)d_in[35];
    const float* p_al = (const float*)d_in[36];
    const float* p_ar = (const float*)d_in[37];
    const float* p_Wres = (const float*)d_in[38];
    const float* p_bias = (const float*)d_in[39];
    const float* p_g = (const float*)d_in[40];
    const float* p_b = (const float*)d_in[41];
    const float* p_Wout = (const float*)d_in[42];
    const float* p_bout = (const float*)d_in[43];

    float* out = (float*)d_out;
    char* wsb = (char*)d_ws;
    unsigned short* xAb = (unsigned short*)(wsb + 0);             // 25.6 MB
    unsigned short* xGb = (unsigned short*)(wsb + 26000000);      // 6.4 MB
    unsigned short* WtB1 = (unsigned short*)(wsb + 33000000);     // weight slots
    unsigned short* WtB2 = WtB1 + 32768;
    unsigned short* WtO1 = WtB2 + 32768;
    unsigned short* WtO2 = WtO1 + 32768;
    unsigned short* WtR  = WtO2 + 32768;   // 512x256 (Wfc|Wres)
    unsigned short* WtRo = WtR + 131072;   // 128x512
    unsigned short* WtP  = WtRo + 65536;   // 512x256
    unsigned short* WtPo = WtP + 131072;   // 128x512
    float* wv   = (float*)(wsb + 34100000);                       // 4x512 f32
    int* heads  = (int*)(wsb + 36300000);                         // 250k int
    int* nxt    = (int*)(wsb + 37400000);                         // 900k int
    unsigned short* h0A = (unsigned short*)(wsb + 41100000);      // 25.6 MB
    unsigned short* h0G = (unsigned short*)(wsb + 66800000);      // 6.4 MB
    unsigned short* R4a = (unsigned short*)(wsb + 73300000);      // 51.2 MB
    unsigned short* G1a = (unsigned short*)(wsb + 124600000);     // 25.6 MB
    unsigned short* G1g = (unsigned short*)(wsb + 150300000);     // 6.4 MB
    unsigned short* A2r = (unsigned short*)(wsb + 156800000);     // 102.4 MB
    unsigned short* A2p = (unsigned short*)(wsb + 259300000);     // 25.6 MB
    unsigned short* R3r = (unsigned short*)(wsb + 285000000);     // 102.4 MB
    unsigned short* R3p = (unsigned short*)(wsb + 387500000);     // 25.6 MB
    uint2* adj  = (uint2*)(wsb + 414000000);                      // 128 MB
    int* deg    = (int*)(wsb + 543000000);                        // 1 MB
    float* F    = (float*)(wsb + 544000000);                      // logit/ex block
    float* elR  = F;               // N_G*4
    float* elP  = F + 100000;      // N_A*4
    float* erR  = F + 500000;      // N_A*4
    float* erP  = F + 900000;      // N_G*4
    float* denR = F + 1000000;     // N_A*4
    float* denP = F + 1400000;     // N_G*4
    float* exR  = F + 1500000;     // E_R*4
    float* exP  = F + 2300000;     // E_P*4
    unsigned short* R4g = (unsigned short*)(wsb + 560000000);     // 12.8 MB

    // memsets for prep
    hipMemsetAsync(deg, 0, NSLOT * 4, stream);
    hipMemsetAsync(heads, 0xFF, NSLOT * 4, stream);
    hipMemsetAsync(denR, 0, 500000 * 4, stream);

    // 1. prep: xcast + wcast + war + adj_fill
    PrepArgs pa;
    pa.xa = x_atom; pa.xg = x_group; pa.xab = xAb; pa.xgb = xGb;
    pa.wc[0] = {b_W1, WtB1, 128, 256, 128, 0};
    pa.wc[1] = {b_W2, WtB2, 256, 128, 256, 0};
    pa.wc[2] = {o_W1, WtO1, 128, 256, 128, 0};
    pa.wc[3] = {o_W2, WtO2, 256, 128, 256, 0};
    pa.wc[4] = {r_Wfc, WtR, 128, 512, 256, 0};
    pa.wc[5] = {r_Wres, WtR, 128, 512, 256, 128};
    pa.wc[6] = {r_Wout, WtRo, 512, 128, 512, 0};
    pa.wc[7] = {p_Wfc, WtP, 128, 512, 256, 0};
    pa.wc[8] = {p_Wres, WtP, 128, 512, 256, 128};
    pa.wc[9] = {p_Wout, WtPo, 512, 128, 512, 0};
    pa.rWfc = r_Wfc; pa.ral = r_al; pa.rar = r_ar;
    pa.pWfc = p_Wfc; pa.pal = p_al; pa.par = p_ar; pa.wv = wv;
    pa.bs = bond_src; pa.bd = bond_dst; pa.os = ov_src; pa.od = ov_dst;
    pa.rs = ref_src; pa.rd = ref_dst; pa.ps = pool_src; pa.pd = pool_dst;
    pa.deg = deg; pa.adj = adj; pa.heads = heads; pa.nxt = nxt;
    k_prep<<<PB_XC + PB_WC + PB_WAR + 3516, 256, 0, stream>>>(pa);

    // 2. GINE gather (16 lanes/node) + node logits
    k_gather_logit<<<GBN + 1954, 256, 0, stream>>>(
        xAb, xGb, ef_bond, ef_ov, bond_src, ov_src, deg, adj, heads, nxt,
        b_eps, o_eps, h0A, h0G, wv, elR, elP, erR, erP);

    // 3. GINE GEMM1 (both) + edge exp/denominators
    k_gemm1_exp<<<2 * NBA + 2 * NBG + 6250, 256, 0, stream>>>(
        h0A, h0G, WtB1, WtO1, b_b1, b_g1, b_be1, o_b1, o_g1, o_be1, R4a, R4g,
        elR, erR, elP, erP, ref_src, ref_dst, pool_src, pool_dst, exR, exP, denR, denP);

    // 4. GAT aggregation (16 lanes/node)
    k_att_gather_all<<<GBN, 256, 0, stream>>>(
        xAb, xGb, exR, exP, denR, denP, ref_src, pool_src, deg, adj, heads, nxt, A2r, A2p);

    // 5. GINE GEMM2 + GATK GEMMs (homogeneous)
    k_gatk_mid<<<NBA + NBG + 4 * NBA + 4 * NBG, 256, 0, stream>>>(
        R4a, R4g, WtB2, WtO2, b_b2, o_b2, G1a, G1g,
        A2r, A2p, xAb, xGb, WtR, WtP,
        r_bias, r_g, r_b, p_bias, p_g, p_b, R3r, R3p);

    // 6. Wout GEMMs -> d_out
    k_gemm_out<<<NBA + NBG, 256, 0, stream>>>(R3r, R3p, WtRo, WtPo, r_bout, p_bout,
                                              G1a, G1g, out);
}

// Round 18
// 499.752 us; speedup vs baseline: 1.0561x; 1.0561x over previous
//
#include <hip/hip_runtime.h>
#include <hip/hip_bf16.h>

#define N_A 100000
#define N_G 25000
#define DD 128
#define E_B 400000
#define E_O 100000
#define E_R 200000
#define E_P 200000
#define EALL 900000
#define NSLOT 250000
#define STRIDE 16
#define NALL 125000
#define GBN 7813   // ceil(125000/16) node-batch blocks

static constexpr float BN_INV_C = 0.99999500003749969f; // 1/sqrt(1+1e-5)

typedef __attribute__((ext_vector_type(8))) short bf16x8;
typedef __attribute__((ext_vector_type(4))) float f32x4;

__device__ __forceinline__ unsigned short f2bf(float f) {
    unsigned u = __float_as_uint(f);
    unsigned r = (u + 0x7FFFu + ((u >> 16) & 1u)) >> 16;
    return (unsigned short)r;
}
__device__ __forceinline__ float bf2f(unsigned short s) {
    return __uint_as_float(((unsigned)s) << 16);
}
__device__ __forceinline__ float lrelu(float v) { return v > 0.f ? v : 0.2f * v; }

// async global->LDS 16B: LDS dest = (wave-uniform base) + lane*16
__device__ __forceinline__ void gload16(const unsigned short* g, unsigned short* l) {
    __builtin_amdgcn_global_load_lds(
        (const __attribute__((address_space(1))) void*)g,
        (__attribute__((address_space(3))) void*)l, 16, 0, 0);
}

// ---------------- prep: xcast + wcast + war + adj_fill in one launch ----------------
struct WcSeg { const float* src; unsigned short* dst; int K; int N; int ldk; int off; };
struct PrepArgs {
    const float* xa; const float* xg;
    unsigned short* xab; unsigned short* xgb;
    WcSeg wc[10];
    const float* rWfc; const float* ral; const float* rar;
    const float* pWfc; const float* pal; const float* par;
    float* wv;
    const int* bs; const int* bd; const int* os; const int* od;
    const int* rs; const int* rd; const int* ps; const int* pd;
    int* deg; uint2* adj; int* heads; int* nxt;
};

#define PB_XC 15625
#define PB_WC 2560
#define PB_WAR 8

__global__ __launch_bounds__(256) void k_prep(PrepArgs p) {
    int bx = blockIdx.x, tid = threadIdx.x;
    if (bx < PB_XC) {
        int t = bx * 256 + tid;
        if (t < N_A * 32) {
            float4 v = *(const float4*)(p.xa + (size_t)t * 4);
            ushort4 o; o.x = f2bf(v.x); o.y = f2bf(v.y); o.z = f2bf(v.z); o.w = f2bf(v.w);
            *(ushort4*)(p.xab + (size_t)t * 4) = o;
        } else {
            int t2 = t - N_A * 32;
            if (t2 < N_G * 32) {
                float4 v = *(const float4*)(p.xg + (size_t)t2 * 4);
                ushort4 o; o.x = f2bf(v.x); o.y = f2bf(v.y); o.z = f2bf(v.z); o.w = f2bf(v.w);
                *(ushort4*)(p.xgb + (size_t)t2 * 4) = o;
            }
        }
    } else if (bx < PB_XC + PB_WC) {
        int b2 = bx - PB_XC;
        WcSeg sg = p.wc[b2 >> 8];
        int t = ((b2 & 255) << 8) + tid;
        if (t < sg.K * sg.N) {
            int n = t % sg.N, k = t / sg.N;
            sg.dst[(size_t)n * sg.ldk + sg.off + k] = f2bf(sg.src[t]);
        }
    } else if (bx < PB_XC + PB_WC + PB_WAR) {
        int b3 = bx - (PB_XC + PB_WC);
        int bsel = b3 >> 1;
        int t = ((b3 & 1) << 8) + tid;   // 512 threads per bsel
        const float* W = bsel < 2 ? p.rWfc : p.pWfc;
        const float* vec = bsel == 0 ? p.ral : bsel == 1 ? p.rar : bsel == 2 ? p.pal : p.par;
        int k = t >> 2, h = t & 3;
        const float* wr = W + (size_t)k * 512 + h * 128;
        const float* av = vec + h * 128;
        float s = 0.f;
        for (int d = 0; d < 128; ++d) s += wr[d] * av[d];
        p.wv[bsel * 512 + t] = s;
    } else {
        int t = (bx - (PB_XC + PB_WC + PB_WAR)) * 256 + tid;
        int e, base, go; const int* S; const int* D;
        if (t < E_B) { e = t; S = p.bs; D = p.bd; base = 0; go = 0; }
        else if (t < E_B + E_O) { e = t - E_B; S = p.os; D = p.od; base = 100000; go = E_B; }
        else if (t < E_B + E_O + E_R) { e = t - (E_B + E_O); S = p.rs; D = p.rd; base = 125000; go = E_B + E_O; }
        else if (t < EALL) { e = t - (E_B + E_O + E_R); S = p.ps; D = p.pd; base = 225000; go = E_B + E_O + E_R; }
        else return;
        int d = D[e], s = S[e];
        int ns = base + d;
        int pos = atomicAdd(&p.deg[ns], 1);
        if (pos < STRIDE) p.adj[(size_t)ns * STRIDE + pos] = make_uint2((unsigned)e, (unsigned)s);
        else p.nxt[go + e] = atomicExch(&p.heads[ns], e);
    }
}

// per-edge GINE accumulate: lane owns 8 dims at l16*8
__device__ __forceinline__ void gine_acc(const unsigned short* __restrict__ xs,
                                         const float* __restrict__ ef,
                                         uint2 es, int l16, float* acc) {
    uint4 xw = *(const uint4*)(xs + (size_t)es.y * DD + l16 * 8);
    float4 e0 = *(const float4*)(ef + (size_t)es.x * DD + l16 * 8);
    float4 e1 = *(const float4*)(ef + (size_t)es.x * DD + l16 * 8 + 4);
    unsigned w[4] = {xw.x, xw.y, xw.z, xw.w};
    float ev[8] = {e0.x, e0.y, e0.z, e0.w, e1.x, e1.y, e1.z, e1.w};
#pragma unroll
    for (int q = 0; q < 4; ++q) {
        acc[q * 2]     += fmaxf(bf2f((unsigned short)(w[q] & 0xffff)) + ev[q * 2], 0.f);
        acc[q * 2 + 1] += fmaxf(bf2f((unsigned short)(w[q] >> 16)) + ev[q * 2 + 1], 0.f);
    }
}

// ---------------- GINE gather: 16 lanes per node, 4 concurrent nodes per wave ----------------
__device__ __forceinline__ void gine16_body(
    int bx, int tid,
    const unsigned short* __restrict__ xAb, const unsigned short* __restrict__ xGb,
    const float* __restrict__ efB, const float* __restrict__ efO,
    const int* __restrict__ bsrc, const int* __restrict__ osrc,
    const int* __restrict__ deg, const uint2* __restrict__ adj,
    const int* __restrict__ heads, const int* __restrict__ nxt,
    const float* __restrict__ beps, const float* __restrict__ oeps,
    unsigned short* __restrict__ h0A, unsigned short* __restrict__ h0G,
    uint2* glbuf, int* degb) {
    int wid = tid >> 6, lane = tid & 63;
    int grp = lane >> 4, l16 = lane & 15;
    int nbase = bx * 16 + wid * 4;
    bool atomside = nbase < N_A;   // 100000 is 16-aligned -> wave-uniform
    const unsigned short* xs = atomside ? xAb : xGb;
    const float* ef = atomside ? efB : efO;
    const int* esrc = atomside ? bsrc : osrc;
    const int* nx = atomside ? nxt : nxt + E_B;
    float ep = 1.0f + (atomside ? beps[0] : oeps[0]);
    unsigned short* h0 = atomside ? h0A : h0G;
    uint2* glw = glbuf + wid * 4 * STRIDE;
    // one 64-lane pass loads all 4 nodes' 16-entry rows
    {
        int nj2 = nbase + grp;
        if (nj2 < NALL) glw[grp * STRIDE + l16] = adj[(size_t)nj2 * STRIDE + l16];
    }
    if (lane < 4) {
        int nj2 = nbase + lane;
        degb[wid * 4 + lane] = (nj2 < NALL) ? deg[nj2] : 0;
    }
    __syncthreads();
    int nj = nbase + grp;
    if (nj >= NALL) return;
    int dd = degb[wid * 4 + grp];
    int cb = min(dd, STRIDE);
    int nn = atomside ? nj : nj - N_A;
    const uint2* gl = glw + grp * STRIDE;
    float acc[8] = {0.f, 0.f, 0.f, 0.f, 0.f, 0.f, 0.f, 0.f};
    int i = 0;
    for (; i + 2 <= cb; i += 2) {
        gine_acc(xs, ef, gl[i], l16, acc);
        gine_acc(xs, ef, gl[i + 1], l16, acc);
    }
    if (i < cb) gine_acc(xs, ef, gl[i], l16, acc);
    if (dd > STRIDE) {
        for (int e = heads[nj]; e >= 0; e = nx[e])
            gine_acc(xs, ef, make_uint2((unsigned)e, (unsigned)esrc[e]), l16, acc);
    }
    uint4 xd = *(const uint4*)(xs + (size_t)nn * DD + l16 * 8);
    unsigned w[4] = {xd.x, xd.y, xd.z, xd.w};
    uint4 o;
    unsigned ow[4];
#pragma unroll
    for (int q = 0; q < 4; ++q) {
        float v0 = ep * bf2f((unsigned short)(w[q] & 0xffff)) + acc[q * 2];
        float v1 = ep * bf2f((unsigned short)(w[q] >> 16)) + acc[q * 2 + 1];
        ow[q] = (unsigned)f2bf(v0) | ((unsigned)f2bf(v1) << 16);
    }
    o.x = ow[0]; o.y = ow[1]; o.z = ow[2]; o.w = ow[3];
    *(uint4*)(h0 + (size_t)nn * DD + l16 * 8) = o;
}

// ---------------- node logits body ----------------
__device__ __forceinline__ void logit_body(
    int t,
    const unsigned short* __restrict__ xAb, const unsigned short* __restrict__ xGb,
    const float* __restrict__ wv,
    float* __restrict__ elR, float* __restrict__ elP,
    float* __restrict__ erR, float* __restrict__ erP) {
    const unsigned short* xr; const float* wl; const float* wr_; float* ol; float* orr; int idx;
    if (t < N_A * 4) {
        idx = t; xr = xAb + (size_t)(t >> 2) * DD; wl = wv + 1024; wr_ = wv + 512;
        ol = elP; orr = erR;
    } else {
        int t2 = t - N_A * 4;
        if (t2 >= N_G * 4) return;
        idx = t2; xr = xGb + (size_t)(t2 >> 2) * DD; wl = wv; wr_ = wv + 1536;
        ol = elR; orr = erP;
    }
    int h = idx & 3;
    float sl = 0.f, sr = 0.f;
#pragma unroll
    for (int k = 0; k < DD; k += 8) {
        uint4 w = *(const uint4*)(xr + k);
        unsigned wa[4] = {w.x, w.y, w.z, w.w};
#pragma unroll
        for (int q = 0; q < 4; ++q) {
            float x0 = bf2f((unsigned short)(wa[q] & 0xffff));
            float x1 = bf2f((unsigned short)(wa[q] >> 16));
            int k0 = (k + q * 2) * 4 + h, k1 = (k + q * 2 + 1) * 4 + h;
            sl += x0 * wl[k0] + x1 * wl[k1];
            sr += x0 * wr_[k0] + x1 * wr_[k1];
        }
    }
    ol[idx] = sl;
    orr[idx] = sr;
}

__global__ __launch_bounds__(256) void k_gather_logit(
    const unsigned short* __restrict__ xAb, const unsigned short* __restrict__ xGb,
    const float* __restrict__ efB, const float* __restrict__ efO,
    const int* __restrict__ bsrc, const int* __restrict__ osrc,
    const int* __restrict__ deg, const uint2* __restrict__ adj,
    const int* __restrict__ heads, const int* __restrict__ nxt,
    const float* __restrict__ beps, const float* __restrict__ oeps,
    unsigned short* __restrict__ h0A, unsigned short* __restrict__ h0G,
    const float* __restrict__ wv,
    float* __restrict__ elR, float* __restrict__ elP,
    float* __restrict__ erR, float* __restrict__ erP) {
    __shared__ uint2 gl[16 * STRIDE];
    __shared__ int degb[16];
    int bx = blockIdx.x;
    if (bx < GBN)
        gine16_body(bx, threadIdx.x, xAb, xGb, efB, efO, bsrc, osrc, deg, adj, heads, nxt,
                    beps, oeps, h0A, h0G, gl, degb);
    else
        logit_body((bx - GBN) * 256 + threadIdx.x, xAb, xGb, wv, elR, elP, erR, erP);
}

// ---------------- edge-parallel exp + denominator body ----------------
__device__ __forceinline__ void exp_body(
    int t,
    const float* __restrict__ elR, const float* __restrict__ erR,
    const float* __restrict__ elP, const float* __restrict__ erP,
    const int* __restrict__ rs, const int* __restrict__ rd,
    const int* __restrict__ ps, const int* __restrict__ pd,
    float* __restrict__ exR, float* __restrict__ exP,
    float* __restrict__ denR, float* __restrict__ denP) {
    if (t < E_R * 4) {
        int e = t >> 2, h = t & 3;
        float v = lrelu(elR[rs[e] * 4 + h] + erR[rd[e] * 4 + h]);
        float x = __expf(v);
        exR[t] = x;
        atomicAdd(&denR[rd[e] * 4 + h], x);
    } else {
        int t2 = t - E_R * 4;
        if (t2 >= E_P * 4) return;
        int e = t2 >> 2, h = t2 & 3;
        float v = lrelu(elP[ps[e] * 4 + h] + erP[pd[e] * 4 + h]);
        float x = __expf(v);
        exP[t2] = x;
        atomicAdd(&denP[pd[e] * 4 + h], x);
    }
}

// per-edge GAT accumulate: lane owns 8 dims
__device__ __forceinline__ void att_acc(const unsigned short* __restrict__ xs,
                                        const float* __restrict__ ex,
                                        uint2 es, int l16, const float* inv,
                                        float acc[4][8]) {
    float4 e4 = *(const float4*)(ex + (size_t)es.x * 4);
    uint4 xw = *(const uint4*)(xs + (size_t)es.y * DD + l16 * 8);
    unsigned w[4] = {xw.x, xw.y, xw.z, xw.w};
    float xv[8];
#pragma unroll
    for (int q = 0; q < 4; ++q) {
        xv[q * 2] = bf2f((unsigned short)(w[q] & 0xffff));
        xv[q * 2 + 1] = bf2f((unsigned short)(w[q] >> 16));
    }
    float a[4] = {e4.x * inv[0], e4.y * inv[1], e4.z * inv[2], e4.w * inv[3]};
#pragma unroll
    for (int h = 0; h < 4; ++h)
#pragma unroll
        for (int q = 0; q < 8; ++q) acc[h][q] += a[h] * xv[q];
}

// ---------------- GAT gather: 16 lanes per node, 4 concurrent nodes per wave ----------------
__global__ __launch_bounds__(256) void k_att_gather_all(
    const unsigned short* __restrict__ xAb, const unsigned short* __restrict__ xGb,
    const float* __restrict__ exR, const float* __restrict__ exP,
    const float* __restrict__ denR, const float* __restrict__ denP,
    const int* __restrict__ rsrc, const int* __restrict__ psrc,
    const int* __restrict__ deg, const uint2* __restrict__ adj,
    const int* __restrict__ heads, const int* __restrict__ nxt,
    unsigned short* __restrict__ A2r, unsigned short* __restrict__ A2p) {
    __shared__ uint2 glbuf[16 * STRIDE];
    __shared__ int degb[16];
    int tid = threadIdx.x;
    int wid = tid >> 6, lane = tid & 63;
    int grp = lane >> 4, l16 = lane & 15;
    int nbase = blockIdx.x * 16 + wid * 4;
    bool atomside = nbase < N_A;
    const unsigned short* xs = atomside ? xGb : xAb;
    const float* ex = atomside ? exR : exP;
    const float* den = atomside ? denR : denP;
    const int* esrc = atomside ? rsrc : psrc;
    const int* nx = atomside ? nxt + (E_B + E_O) : nxt + (E_B + E_O + E_R);
    unsigned short* A2b = atomside ? A2r : A2p;
    uint2* glw = glbuf + wid * 4 * STRIDE;
    {
        int nj2 = nbase + grp;
        if (nj2 < NALL) glw[grp * STRIDE + l16] = adj[(size_t)(125000 + nj2) * STRIDE + l16];
    }
    if (lane < 4) {
        int nj2 = nbase + lane;
        degb[wid * 4 + lane] = (nj2 < NALL) ? deg[125000 + nj2] : 0;
    }
    __syncthreads();
    int nj = nbase + grp;
    if (nj >= NALL) return;
    int dd = degb[wid * 4 + grp];
    int cb = min(dd, STRIDE);
    int nn = atomside ? nj : nj - N_A;
    const uint2* gl = glw + grp * STRIDE;
    unsigned short* A2 = A2b + (size_t)nn * 512;
    float4 dv = *(const float4*)(den + (size_t)nn * 4);
    float inv[4];
    inv[0] = 1.f / fmaxf(dv.x, 1e-9f);
    inv[1] = 1.f / fmaxf(dv.y, 1e-9f);
    inv[2] = 1.f / fmaxf(dv.z, 1e-9f);
    inv[3] = 1.f / fmaxf(dv.w, 1e-9f);
    float acc[4][8] = {};
    int i = 0;
    for (; i + 2 <= cb; i += 2) {
        att_acc(xs, ex, gl[i], l16, inv, acc);
        att_acc(xs, ex, gl[i + 1], l16, inv, acc);
    }
    if (i < cb) att_acc(xs, ex, gl[i], l16, inv, acc);
    if (dd > STRIDE) {
        for (int e = heads[125000 + nj]; e >= 0; e = nx[e])
            att_acc(xs, ex, make_uint2((unsigned)e, (unsigned)esrc[e]), l16, inv, acc);
    }
#pragma unroll
    for (int h = 0; h < 4; ++h) {
        unsigned ow[4];
#pragma unroll
        for (int q = 0; q < 4; ++q)
            ow[q] = (unsigned)f2bf(acc[h][q * 2]) | ((unsigned)f2bf(acc[h][q * 2 + 1]) << 16);
        uint4 o; o.x = ow[0]; o.y = ow[1]; o.z = ow[2]; o.w = ow[3];
        *(uint4*)(A2 + h * 128 + l16 * 8) = o;
    }
}

// ---------------- bf16 MFMA GEMM body: 4 waves, 128x128 tile (R15 single-buffer form) ----------------
template <int EPI, int OUTBF, int GATK>
__device__ __forceinline__ void gemm_body(
    const unsigned short* __restrict__ A, const unsigned short* __restrict__ Bt,
    void* __restrict__ C, int M, int N, int K,
    const float* __restrict__ bias, const float* __restrict__ g,
    const float* __restrict__ be, const unsigned short* __restrict__ addbf,
    const unsigned short* __restrict__ Axd, int bxx, int byy,
    unsigned short* As, unsigned short* Bs) {
    int tid = threadIdx.x;
    int wave = tid >> 6, lane = tid & 63;
    int wr = wave >> 1, wc = wave & 1;
    int row0 = byy * 128, col0 = bxx * 128;
    int l16 = lane & 15, q = lane >> 4;
    int r0s = wave * 16 + (lane >> 2);
    int r1s = r0s + 64;
    int swl = (lane ^ (lane >> 2) ^ (lane >> 4)) & 3;
    int swr = (l16 ^ (l16 >> 2)) & 3;
    unsigned short* ldsA0 = As + wave * 512;
    unsigned short* ldsA1 = As + 2048 + wave * 512;
    unsigned short* ldsB0 = Bs + wave * 512;
    unsigned short* ldsB1 = Bs + 2048 + wave * 512;
    f32x4 acc[4][4] = {};
    for (int k0 = 0; k0 < K; k0 += 32) {
        __syncthreads();
        {
            int kk = k0 + swl * 8;
            int ra0 = min(row0 + r0s, M - 1);
            int ra1 = min(row0 + r1s, M - 1);
            const unsigned short *pa0, *pa1;
            if (GATK) {
                if (k0 < 128) {
                    pa0 = A + (size_t)ra0 * 512 + col0 + kk;
                    pa1 = A + (size_t)ra1 * 512 + col0 + kk;
                } else {
                    pa0 = Axd + (size_t)ra0 * 128 + (kk - 128);
                    pa1 = Axd + (size_t)ra1 * 128 + (kk - 128);
                }
            } else {
                pa0 = A + (size_t)ra0 * K + kk;
                pa1 = A + (size_t)ra1 * K + kk;
            }
            gload16(pa0, ldsA0);
            gload16(pa1, ldsA1);
            gload16(Bt + (size_t)(col0 + r0s) * K + kk, ldsB0);
            gload16(Bt + (size_t)(col0 + r1s) * K + kk, ldsB1);
        }
        __syncthreads();
        bf16x8 af[4], bfr[4];
#pragma unroll
        for (int i = 0; i < 4; ++i) {
            int row = wr * 64 + i * 16 + l16;
            af[i] = *(const bf16x8*)(&As[row * 32 + ((q ^ swr) * 8)]);
        }
#pragma unroll
        for (int j = 0; j < 4; ++j) {
            int row = wc * 64 + j * 16 + l16;
            bfr[j] = *(const bf16x8*)(&Bs[row * 32 + ((q ^ swr) * 8)]);
        }
#pragma unroll
        for (int i = 0; i < 4; ++i)
#pragma unroll
            for (int j = 0; j < 4; ++j)
                acc[i][j] = __builtin_amdgcn_mfma_f32_16x16x32_bf16(af[i], bfr[j], acc[i][j], 0, 0, 0);
    }
    int rq = (lane >> 4) * 4;
#pragma unroll
    for (int i = 0; i < 4; ++i) {
#pragma unroll
        for (int reg = 0; reg < 4; ++reg) {
            int r = row0 + wr * 64 + i * 16 + rq + reg;
            if (r >= M) continue;
#pragma unroll
            for (int j = 0; j < 4; ++j) {
                int c = col0 + wc * 64 + j * 16 + l16;
                float v = acc[i][j][reg];
                size_t idx = (size_t)r * N + c;
                v += bias[c];
                if (EPI == 2) {
                    v = g[c] * (v * BN_INV_C) + be[c];
                    v = fmaxf(v, 0.f);
                }
                if (EPI == 3) {
                    ((float*)C)[idx] = v + bf2f(addbf[idx]);
                } else if (OUTBF) {
                    ((unsigned short*)C)[idx] = f2bf(v);
                } else {
                    ((float*)C)[idx] = v;
                }
            }
        }
    }
}

#define NBA 782
#define NBG 196

// GINE GEMM1 (both relations) + edge exp: 1956 + 6250 blocks
__global__ __launch_bounds__(256) void k_gemm1_exp(
    const unsigned short* h0A, const unsigned short* h0G,
    const unsigned short* WtB1, const unsigned short* WtO1,
    const float* bb1, const float* bg1, const float* bbe1,
    const float* ob1, const float* og1, const float* obe1,
    unsigned short* R4a, unsigned short* R4g,
    const float* elR, const float* erR, const float* elP, const float* erP,
    const int* rs, const int* rd, const int* ps, const int* pd,
    float* exR, float* exP, float* denR, float* denP) {
    __shared__ unsigned short As[4096];
    __shared__ unsigned short Bs[4096];
    int b = blockIdx.x;
    if (b < 2 * NBA)
        gemm_body<2, 1, 0>(h0A, WtB1, R4a, N_A, 256, 128, bb1, bg1, bbe1, nullptr, nullptr,
                           b & 1, b >> 1, As, Bs);
    else if (b < 2 * NBA + 2 * NBG) {
        int b2 = b - 2 * NBA;
        gemm_body<2, 1, 0>(h0G, WtO1, R4g, N_G, 256, 128, ob1, og1, obe1, nullptr, nullptr,
                           b2 & 1, b2 >> 1, As, Bs);
    } else {
        int t = (b - (2 * NBA + 2 * NBG)) * 256 + threadIdx.x;
        exp_body(t, elR, erR, elP, erP, rs, rd, ps, pd, exR, exP, denR, denP);
    }
}

// GINE GEMM2 (978) + GATK GEMMs (3912): homogeneous gemm blocks
__global__ __launch_bounds__(256) void k_gatk_mid(
    const unsigned short* R4a, const unsigned short* R4g,
    const unsigned short* WtB2, const unsigned short* WtO2,
    const float* bb2, const float* ob2,
    unsigned short* G1a, unsigned short* G1g,
    const unsigned short* A2r, const unsigned short* A2p,
    const unsigned short* xAb, const unsigned short* xGb,
    const unsigned short* WtR, const unsigned short* WtP,
    const float* rbias, const float* rg, const float* rb,
    const float* pbias, const float* pg, const float* pb,
    unsigned short* R3r, unsigned short* R3p) {
    __shared__ unsigned short As[4096];
    __shared__ unsigned short Bs[4096];
    int b = blockIdx.x;
    if (b < NBA)
        gemm_body<1, 1, 0>(R4a, WtB2, G1a, N_A, 128, 256, bb2, nullptr, nullptr, nullptr, nullptr,
                           0, b, As, Bs);
    else if (b < NBA + NBG)
        gemm_body<1, 1, 0>(R4g, WtO2, G1g, N_G, 128, 256, ob2, nullptr, nullptr, nullptr, nullptr,
                           0, b - NBA, As, Bs);
    else if (b < NBA + NBG + 4 * NBA) {
        int b3 = b - (NBA + NBG);
        gemm_body<2, 1, 1>(A2r, WtR, R3r, N_A, 512, 256, rbias, rg, rb, nullptr, xAb,
                           b3 & 3, b3 >> 2, As, Bs);
    } else {
        int b4 = b - (NBA + NBG + 4 * NBA);
        gemm_body<2, 1, 1>(A2p, WtP, R3p, N_G, 512, 256, pbias, pg, pb, nullptr, xGb,
                           b4 & 3, b4 >> 2, As, Bs);
    }
}

// Wout GEMMs (both): 978 blocks, single f32 write of d_out
__global__ __launch_bounds__(256) void k_gemm_out(
    const unsigned short* R3r, const unsigned short* R3p,
    const unsigned short* WtRo, const unsigned short* WtPo,
    const float* rbout, const float* pbout,
    const unsigned short* G1a, const unsigned short* G1g,
    float* out) {
    __shared__ unsigned short As[4096];
    __shared__ unsigned short Bs[4096];
    int b = blockIdx.x;
    if (b < NBA)
        gemm_body<3, 0, 0>(R3r, WtRo, out, N_A, 128, 512, rbout, nullptr, nullptr, G1a, nullptr,
                           0, b, As, Bs);
    else
        gemm_body<3, 0, 0>(R3p, WtPo, out + (size_t)N_A * DD, N_G, 128, 512, pbout, nullptr, nullptr,
                           G1g, nullptr, 0, b - NBA, As, Bs);
}

extern "C" void kernel_launch(void* const* d_in, const int* in_sizes, int n_in,
                              void* d_out, int out_size, void* d_ws, size_t ws_size,
                              hipStream_t stream) {
    const float* x_atom = (const float*)d_in[0];
    const float* x_group = (const float*)d_in[1];
    const float* ef_bond = (const float*)d_in[2];
    const float* ef_ov = (const float*)d_in[3];
    const int* bond_src = (const int*)d_in[4];
    const int* bond_dst = (const int*)d_in[5];
    const int* ov_src = (const int*)d_in[6];
    const int* ov_dst = (const int*)d_in[7];
    const int* ref_src = (const int*)d_in[8];
    const int* ref_dst = (const int*)d_in[9];
    const int* pool_src = (const int*)d_in[10];
    const int* pool_dst = (const int*)d_in[11];
    const float* b_eps = (const float*)d_in[12];
    const float* b_W1 = (const float*)d_in[13];
    const float* b_b1 = (const float*)d_in[14];
    const float* b_g1 = (const float*)d_in[15];
    const float* b_be1 = (const float*)d_in[16];
    const float* b_W2 = (const float*)d_in[17];
    const float* b_b2 = (const float*)d_in[18];
    const float* o_eps = (const float*)d_in[19];
    const float* o_W1 = (const float*)d_in[20];
    const float* o_b1 = (const float*)d_in[21];
    const float* o_g1 = (const float*)d_in[22];
    const float* o_be1 = (const float*)d_in[23];
    const float* o_W2 = (const float*)d_in[24];
    const float* o_b2 = (const float*)d_in[25];
    const float* r_Wfc = (const float*)d_in[26];
    const float* r_al = (const float*)d_in[27];
    const float* r_ar = (const float*)d_in[28];
    const float* r_Wres = (const float*)d_in[29];
    const float* r_bias = (const float*)d_in[30];
    const float* r_g = (const float*)d_in[31];
    const float* r_b = (const float*)d_in[32];
    const float* r_Wout = (const float*)d_in[33];
    const float* r_bout = (const float*)d_in[34];
    const float* p_Wfc = (const float*)d_in[35];
    const float* p_al = (const float*)d_in[36];
    const float* p_ar = (const float*)d_in[37];
    const float* p_Wres = (const float*)d_in[38];
    const float* p_bias = (const float*)d_in[39];
    const float* p_g = (const float*)d_in[40];
    const float* p_b = (const float*)d_in[41];
    const float* p_Wout = (const float*)d_in[42];
    const float* p_bout = (const float*)d_in[43];

    float* out = (float*)d_out;
    char* wsb = (char*)d_ws;
    unsigned short* xAb = (unsigned short*)(wsb + 0);             // 25.6 MB
    unsigned short* xGb = (unsigned short*)(wsb + 26000000);      // 6.4 MB
    unsigned short* WtB1 = (unsigned short*)(wsb + 33000000);     // weight slots
    unsigned short* WtB2 = WtB1 + 32768;
    unsigned short* WtO1 = WtB2 + 32768;
    unsigned short* WtO2 = WtO1 + 32768;
    unsigned short* WtR  = WtO2 + 32768;   // 512x256 (Wfc|Wres)
    unsigned short* WtRo = WtR + 131072;   // 128x512
    unsigned short* WtP  = WtRo + 65536;   // 512x256
    unsigned short* WtPo = WtP + 131072;   // 128x512
    float* wv   = (float*)(wsb + 34100000);                       // 4x512 f32
    int* heads  = (int*)(wsb + 36300000);                         // 250k int
    int* nxt    = (int*)(wsb + 37400000);                         // 900k int
    unsigned short* h0A = (unsigned short*)(wsb + 41100000);      // 25.6 MB
    unsigned short* h0G = (unsigned short*)(wsb + 66800000);      // 6.4 MB
    unsigned short* R4a = (unsigned short*)(wsb + 73300000);      // 51.2 MB
    unsigned short* G1a = (unsigned short*)(wsb + 124600000);     // 25.6 MB
    unsigned short* G1g = (unsigned short*)(wsb + 150300000);     // 6.4 MB
    unsigned short* A2r = (unsigned short*)(wsb + 156800000);     // 102.4 MB
    unsigned short* A2p = (unsigned short*)(wsb + 259300000);     // 25.6 MB
    unsigned short* R3r = (unsigned short*)(wsb + 285000000);     // 102.4 MB
    unsigned short* R3p = (unsigned short*)(wsb + 387500000);     // 25.6 MB
    uint2* adj  = (uint2*)(wsb + 414000000);                      // 32 MB (250k x 16 x 8B)
    int* deg    = (int*)(wsb + 543000000);                        // 1 MB
    float* F    = (float*)(wsb + 544000000);                      // logit/ex block
    float* elR  = F;               // N_G*4
    float* elP  = F + 100000;      // N_A*4
    float* erR  = F + 500000;      // N_A*4
    float* erP  = F + 900000;      // N_G*4
    float* denR = F + 1000000;     // N_A*4
    float* denP = F + 1400000;     // N_G*4
    float* exR  = F + 1500000;     // E_R*4
    float* exP  = F + 2300000;     // E_P*4
    unsigned short* R4g = (unsigned short*)(wsb + 560000000);     // 12.8 MB

    // memsets for prep
    hipMemsetAsync(deg, 0, NSLOT * 4, stream);
    hipMemsetAsync(heads, 0xFF, NSLOT * 4, stream);
    hipMemsetAsync(denR, 0, 500000 * 4, stream);

    // 1. prep: xcast + wcast + war + adj_fill
    PrepArgs pa;
    pa.xa = x_atom; pa.xg = x_group; pa.xab = xAb; pa.xgb = xGb;
    pa.wc[0] = {b_W1, WtB1, 128, 256, 128, 0};
    pa.wc[1] = {b_W2, WtB2, 256, 128, 256, 0};
    pa.wc[2] = {o_W1, WtO1, 128, 256, 128, 0};
    pa.wc[3] = {o_W2, WtO2, 256, 128, 256, 0};
    pa.wc[4] = {r_Wfc, WtR, 128, 512, 256, 0};
    pa.wc[5] = {r_Wres, WtR, 128, 512, 256, 128};
    pa.wc[6] = {r_Wout, WtRo, 512, 128, 512, 0};
    pa.wc[7] = {p_Wfc, WtP, 128, 512, 256, 0};
    pa.wc[8] = {p_Wres, WtP, 128, 512, 256, 128};
    pa.wc[9] = {p_Wout, WtPo, 512, 128, 512, 0};
    pa.rWfc = r_Wfc; pa.ral = r_al; pa.rar = r_ar;
    pa.pWfc = p_Wfc; pa.pal = p_al; pa.par = p_ar; pa.wv = wv;
    pa.bs = bond_src; pa.bd = bond_dst; pa.os = ov_src; pa.od = ov_dst;
    pa.rs = ref_src; pa.rd = ref_dst; pa.ps = pool_src; pa.pd = pool_dst;
    pa.deg = deg; pa.adj = adj; pa.heads = heads; pa.nxt = nxt;
    k_prep<<<PB_XC + PB_WC + PB_WAR + 3516, 256, 0, stream>>>(pa);

    // 2. GINE gather (16 lanes/node) + node logits
    k_gather_logit<<<GBN + 1954, 256, 0, stream>>>(
        xAb, xGb, ef_bond, ef_ov, bond_src, ov_src, deg, adj, heads, nxt,
        b_eps, o_eps, h0A, h0G, wv, elR, elP, erR, erP);

    // 3. GINE GEMM1 (both) + edge exp/denominators
    k_gemm1_exp<<<2 * NBA + 2 * NBG + 6250, 256, 0, stream>>>(
        h0A, h0G, WtB1, WtO1, b_b1, b_g1, b_be1, o_b1, o_g1, o_be1, R4a, R4g,
        elR, erR, elP, erP, ref_src, ref_dst, pool_src, pool_dst, exR, exP, denR, denP);

    // 4. GAT aggregation (16 lanes/node)
    k_att_gather_all<<<GBN, 256, 0, stream>>>(
        xAb, xGb, exR, exP, denR, denP, ref_src, pool_src, deg, adj, heads, nxt, A2r, A2p);

    // 5. GINE GEMM2 + GATK GEMMs (homogeneous)
    k_gatk_mid<<<NBA + NBG + 4 * NBA + 4 * NBG, 256, 0, stream>>>(
        R4a, R4g, WtB2, WtO2, b_b2, o_b2, G1a, G1g,
        A2r, A2p, xAb, xGb, WtR, WtP,
        r_bias, r_g, r_b, p_bias, p_g, p_b, R3r, R3p);

    // 6. Wout GEMMs -> d_out
    k_gemm_out<<<NBA + NBG, 256, 0, stream>>>(R3r, R3p, WtRo, WtPo, r_bout, p_bout,
                                              G1a, G1g, out);
}